// Round 1
// baseline (913.546 us; speedup 1.0000x reference)
//
#include <hip/hip_runtime.h>
#include <math.h>

#define NN 50000
#define EE 800000
#define DD 128
#define HH 8
#define DKK 16

// ---------------------------------------------------------------------------
// Kernel 1: node projections  Qn = q @ Wq,  Vn = v @ Wv   ([N,128] x [128,128])
// 64-node tile per block, 256 threads, 4x8 register micro-tile per thread.
// ---------------------------------------------------------------------------
__global__ __launch_bounds__(256) void node_proj_kernel(
    const float* __restrict__ q, const float* __restrict__ v,
    const float* __restrict__ Wq, const float* __restrict__ Wv,
    float* __restrict__ Qn, float* __restrict__ Vn)
{
  __shared__ float xl[64 * 130];          // padded stride 130 -> conflict-free reads
  const int tid = threadIdx.x;
  const int n0 = blockIdx.x * 64;
  const int jg = tid & 15;                // output cols jg*8 .. jg*8+7
  const int rg = tid >> 4;                // rows rg*4 .. rg*4+3

  const float* X[2] = { q, v };
  const float* W[2] = { Wq, Wv };
  float* O[2] = { Qn, Vn };

  for (int m = 0; m < 2; ++m) {
    __syncthreads();                      // protect xl reuse across m
    const float* x = X[m];
    #pragma unroll 4
    for (int p = 0; p < 32; ++p) {        // stage 64x128 input tile
      int flat = p * 256 + tid;
      int i = flat >> 7, c = flat & 127;
      int n = n0 + i;
      xl[i * 130 + c] = (n < NN) ? x[(size_t)n * DD + c] : 0.0f;
    }
    __syncthreads();

    const float* Wm = W[m];
    float acc[4][8];
    #pragma unroll
    for (int r = 0; r < 4; ++r)
      #pragma unroll
      for (int j = 0; j < 8; ++j) acc[r][j] = 0.0f;

    for (int c = 0; c < 128; ++c) {
      float4 w0 = *(const float4*)&Wm[c * DD + jg * 8];
      float4 w1 = *(const float4*)&Wm[c * DD + jg * 8 + 4];
      #pragma unroll
      for (int r = 0; r < 4; ++r) {
        float xr = xl[(rg * 4 + r) * 130 + c];
        acc[r][0] = fmaf(xr, w0.x, acc[r][0]);
        acc[r][1] = fmaf(xr, w0.y, acc[r][1]);
        acc[r][2] = fmaf(xr, w0.z, acc[r][2]);
        acc[r][3] = fmaf(xr, w0.w, acc[r][3]);
        acc[r][4] = fmaf(xr, w1.x, acc[r][4]);
        acc[r][5] = fmaf(xr, w1.y, acc[r][5]);
        acc[r][6] = fmaf(xr, w1.z, acc[r][6]);
        acc[r][7] = fmaf(xr, w1.w, acc[r][7]);
      }
    }

    float* o = O[m];
    #pragma unroll
    for (int r = 0; r < 4; ++r) {
      int n = n0 + rg * 4 + r;
      if (n < NN) {
        float4 o0 = { acc[r][0], acc[r][1], acc[r][2], acc[r][3] };
        float4 o1 = { acc[r][4], acc[r][5], acc[r][6], acc[r][7] };
        *(float4*)&o[(size_t)n * DD + jg * 8]     = o0;
        *(float4*)&o[(size_t)n * DD + jg * 8 + 4] = o1;
      }
    }
  }
}

// ---------------------------------------------------------------------------
// Kernel 2: fused per-edge  Ke = (k[src]+e) @ Wk,  scores = leaky(Q.K^T/4),
// softmax over heads, He = A @ Ve, atomic scatter-sum into out[dst].
// 64 edges per block, 512 threads.
// LDS: Wk (64KB) + one 8704-float buffer reused as kke -> Ke -> He (~100KB).
// ---------------------------------------------------------------------------
__global__ __launch_bounds__(512) void edge_attn_kernel(
    const float* __restrict__ k, const float* __restrict__ e,
    const int* __restrict__ src, const int* __restrict__ dst,
    const float* __restrict__ Wk,
    const float* __restrict__ Qn, const float* __restrict__ Vn,
    float* __restrict__ out)
{
  __shared__ float Wk_l[DD * DD];       // 16384 floats
  __shared__ float buf[128 * 68];       // kke [128][68], then Ke/He [64][132]
  __shared__ int s_src[64], s_dst[64];

  const int tid = threadIdx.x;
  const size_t e0 = (size_t)blockIdx.x * 64;

  // ---- stage Wk (coalesced float4) + edge indices ----
  #pragma unroll
  for (int p = 0; p < 8; ++p) {
    int f = p * 512 + tid;              // float4 index, 4096 total
    ((float4*)Wk_l)[f] = ((const float4*)Wk)[f];
  }
  if (tid < 64) {
    s_src[tid] = src[e0 + tid];
    s_dst[tid] = dst[e0 + tid];
  }
  __syncthreads();

  // ---- stage kke[c][i] = k[src_i][c] + e[e0+i][c]  (transposed, stride 68) ----
  for (int p = 0; p < 16; ++p) {
    int flat = p * 512 + tid;           // 8192 = 64 * 128
    int i = flat >> 7, c = flat & 127;
    buf[c * 68 + i] = k[(size_t)s_src[i] * DD + c] + e[(e0 + i) * DD + c];
  }
  __syncthreads();

  // ---- phase 1: Ke[i][j] = sum_c kke[c][i] * Wk[c][j] ----
  {
    const int ig = tid >> 6;            // wave-uniform edge group: edges ig*8..+7
    const int cg = tid & 63;            // cols cg*2, cg*2+1
    float acc[8][2];
    #pragma unroll
    for (int r = 0; r < 8; ++r) { acc[r][0] = 0.0f; acc[r][1] = 0.0f; }

    for (int c = 0; c < 128; ++c) {
      float4 a0 = *(const float4*)&buf[c * 68 + ig * 8];      // broadcast in wave
      float4 a1 = *(const float4*)&buf[c * 68 + ig * 8 + 4];
      float2 w  = *(const float2*)&Wk_l[c * DD + cg * 2];     // 2-way (free)
      float a[8] = { a0.x, a0.y, a0.z, a0.w, a1.x, a1.y, a1.z, a1.w };
      #pragma unroll
      for (int r = 0; r < 8; ++r) {
        acc[r][0] = fmaf(a[r], w.x, acc[r][0]);
        acc[r][1] = fmaf(a[r], w.y, acc[r][1]);
      }
    }
    __syncthreads();                    // everyone done reading kke
    #pragma unroll
    for (int r = 0; r < 8; ++r) {       // Ke overwrites buf, stride 132 (padded)
      float2 t = { acc[r][0], acc[r][1] };
      *(float2*)&buf[(ig * 8 + r) * 132 + cg * 2] = t;
    }
    __syncthreads();
  }

  // ---- phase 2: per (edge i, head h) lane ----
  {
    const int i = tid >> 3, h = tid & 7;
    const int sn = s_src[i], dn = s_dst[i];

    float Qr[16];
    #pragma unroll
    for (int d0 = 0; d0 < 16; d0 += 4) {
      float4 t = *(const float4*)&Qn[(size_t)dn * DD + h * DKK + d0];
      Qr[d0] = t.x; Qr[d0 + 1] = t.y; Qr[d0 + 2] = t.z; Qr[d0 + 3] = t.w;
    }

    float sc[8];
    #pragma unroll
    for (int g = 0; g < 8; ++g) {
      float a = 0.0f;
      #pragma unroll
      for (int d0 = 0; d0 < 16; d0 += 4) {
        float4 kv = *(const float4*)&buf[i * 132 + g * DKK + d0];
        a = fmaf(Qr[d0], kv.x, a);
        a = fmaf(Qr[d0 + 1], kv.y, a);
        a = fmaf(Qr[d0 + 2], kv.z, a);
        a = fmaf(Qr[d0 + 3], kv.w, a);
      }
      a *= 0.25f;                        // 1/sqrt(16)
      sc[g] = (a >= 0.0f) ? a : 0.01f * a;   // leaky_relu
    }

    float mx = sc[0];
    #pragma unroll
    for (int g = 1; g < 8; ++g) mx = fmaxf(mx, sc[g]);
    float sum = 0.0f;
    #pragma unroll
    for (int g = 0; g < 8; ++g) { sc[g] = __expf(sc[g] - mx); sum += sc[g]; }
    float rs = 1.0f / sum;

    float he[16];
    #pragma unroll
    for (int d = 0; d < 16; ++d) he[d] = 0.0f;
    #pragma unroll
    for (int g = 0; g < 8; ++g) {
      float a = sc[g] * rs;
      #pragma unroll
      for (int d0 = 0; d0 < 16; d0 += 4) {
        float4 vv = *(const float4*)&Vn[(size_t)sn * DD + g * DKK + d0];
        he[d0]     = fmaf(a, vv.x, he[d0]);
        he[d0 + 1] = fmaf(a, vv.y, he[d0 + 1]);
        he[d0 + 2] = fmaf(a, vv.z, he[d0 + 2]);
        he[d0 + 3] = fmaf(a, vv.w, he[d0 + 3]);
      }
    }

    __syncthreads();                    // all Ke reads done before overwrite
    #pragma unroll
    for (int d0 = 0; d0 < 16; d0 += 4) {
      float4 t = { he[d0], he[d0 + 1], he[d0 + 2], he[d0 + 3] };
      *(float4*)&buf[i * 132 + h * DKK + d0] = t;   // He, stride 132
    }
    __syncthreads();
  }

  // ---- coalesced atomic scatter: out[dst_i] += He[i] ----
  for (int p = 0; p < 16; ++p) {
    int flat = p * 512 + tid;
    int i2 = flat >> 7, d = flat & 127;
    atomicAdd(&out[(size_t)s_dst[i2] * DD + d], buf[i2 * 132 + d]);
  }
}

// ---------------------------------------------------------------------------
extern "C" void kernel_launch(void* const* d_in, const int* in_sizes, int n_in,
                              void* d_out, int out_size, void* d_ws, size_t ws_size,
                              hipStream_t stream) {
  const float* q  = (const float*)d_in[0];
  const float* k  = (const float*)d_in[1];
  const float* v  = (const float*)d_in[2];
  const float* e  = (const float*)d_in[3];
  const int*   src = (const int*)d_in[4];
  const int*   dst = (const int*)d_in[5];
  const float* Wq = (const float*)d_in[6];
  const float* Wk = (const float*)d_in[7];
  const float* Wv = (const float*)d_in[8];

  float* out = (float*)d_out;
  float* ws  = (float*)d_ws;
  float* Qn = ws;                          // [N,128] f32
  float* Vn = ws + (size_t)NN * DD;        // [N,128] f32  (51.2 MB total)

  hipMemsetAsync(d_out, 0, (size_t)NN * DD * sizeof(float), stream);
  node_proj_kernel<<<(NN + 63) / 64, 256, 0, stream>>>(q, v, Wq, Wv, Qn, Vn);
  edge_attn_kernel<<<EE / 64, 512, 0, stream>>>(k, e, src, dst, Wk, Qn, Vn, out);
}

// Round 2
// 502.908 us; speedup vs baseline: 1.8165x; 1.8165x over previous
//
#include <hip/hip_runtime.h>
#include <hip/hip_bf16.h>
#include <math.h>

#define NN 50000
#define EE 800000
#define DD 128
#define HH 8
#define DKK 16

typedef __attribute__((ext_vector_type(8))) short short8;
typedef __attribute__((ext_vector_type(4))) float f32x4;
typedef __attribute__((ext_vector_type(4))) unsigned short ushort4v;
typedef __attribute__((ext_vector_type(8))) unsigned short ushort8v;

static __device__ __forceinline__ unsigned short f2bf(float x) {
  __hip_bfloat16 h = __float2bfloat16(x);   // RNE
  return *reinterpret_cast<unsigned short*>(&h);
}
static __device__ __forceinline__ float bf2f(unsigned short u) {
  return __uint_as_float(((unsigned int)u) << 16);
}

// ---------------------------------------------------------------------------
// Prep: WkT[j][c] = bf16(Wk[c][j])  (128x128, so B-fragments read contiguous k)
// ---------------------------------------------------------------------------
__global__ void prep_wkt_kernel(const float* __restrict__ Wk,
                                unsigned short* __restrict__ WkT) {
  int c = blockIdx.x;     // 128 blocks
  int j = threadIdx.x;    // 128 threads
  WkT[j * DD + c] = f2bf(Wk[c * DD + j]);
}

// ---------------------------------------------------------------------------
// Kernel 1: node projections  Qn = q @ Wq,  Vn = v @ Wv  (fp32, unchanged)
// ---------------------------------------------------------------------------
__global__ __launch_bounds__(256) void node_proj_kernel(
    const float* __restrict__ q, const float* __restrict__ v,
    const float* __restrict__ Wq, const float* __restrict__ Wv,
    float* __restrict__ Qn, float* __restrict__ Vn)
{
  __shared__ float xl[64 * 130];
  const int tid = threadIdx.x;
  const int n0 = blockIdx.x * 64;
  const int jg = tid & 15;
  const int rg = tid >> 4;

  const float* X[2] = { q, v };
  const float* W[2] = { Wq, Wv };
  float* O[2] = { Qn, Vn };

  for (int m = 0; m < 2; ++m) {
    __syncthreads();
    const float* x = X[m];
    #pragma unroll 4
    for (int p = 0; p < 32; ++p) {
      int flat = p * 256 + tid;
      int i = flat >> 7, c = flat & 127;
      int n = n0 + i;
      xl[i * 130 + c] = (n < NN) ? x[(size_t)n * DD + c] : 0.0f;
    }
    __syncthreads();

    const float* Wm = W[m];
    float acc[4][8];
    #pragma unroll
    for (int r = 0; r < 4; ++r)
      #pragma unroll
      for (int j = 0; j < 8; ++j) acc[r][j] = 0.0f;

    for (int c = 0; c < 128; ++c) {
      float4 w0 = *(const float4*)&Wm[c * DD + jg * 8];
      float4 w1 = *(const float4*)&Wm[c * DD + jg * 8 + 4];
      #pragma unroll
      for (int r = 0; r < 4; ++r) {
        float xr = xl[(rg * 4 + r) * 130 + c];
        acc[r][0] = fmaf(xr, w0.x, acc[r][0]);
        acc[r][1] = fmaf(xr, w0.y, acc[r][1]);
        acc[r][2] = fmaf(xr, w0.z, acc[r][2]);
        acc[r][3] = fmaf(xr, w0.w, acc[r][3]);
        acc[r][4] = fmaf(xr, w1.x, acc[r][4]);
        acc[r][5] = fmaf(xr, w1.y, acc[r][5]);
        acc[r][6] = fmaf(xr, w1.z, acc[r][6]);
        acc[r][7] = fmaf(xr, w1.w, acc[r][7]);
      }
    }

    float* o = O[m];
    #pragma unroll
    for (int r = 0; r < 4; ++r) {
      int n = n0 + rg * 4 + r;
      if (n < NN) {
        float4 o0 = { acc[r][0], acc[r][1], acc[r][2], acc[r][3] };
        float4 o1 = { acc[r][4], acc[r][5], acc[r][6], acc[r][7] };
        *(float4*)&o[(size_t)n * DD + jg * 8]     = o0;
        *(float4*)&o[(size_t)n * DD + jg * 8 + 4] = o1;
      }
    }
  }
}

// ---------------------------------------------------------------------------
// Kernel 2: fused edge attention. Phase 1 now bf16 MFMA (16x16x32).
// LDS: WkT bf16 [128][136] (34.8KB, reused as He f32 [64][132]),
//      kke bf16 [64][136], Ke bf16 [64][136]  -> ~70KB -> 2 blocks/CU.
// ---------------------------------------------------------------------------
__global__ __launch_bounds__(512, 4) void edge_attn_kernel(
    const float* __restrict__ k, const float* __restrict__ e,
    const int* __restrict__ src, const int* __restrict__ dst,
    const unsigned short* __restrict__ WkT,
    const float* __restrict__ Qn, const float* __restrict__ Vn,
    float* __restrict__ out)
{
  __shared__ __align__(16) unsigned short wk_l[DD * 136];   // 34816 B
  __shared__ __align__(16) unsigned short kke_l[64 * 136];  // 17408 B
  __shared__ __align__(16) unsigned short ke_l[64 * 136];   // 17408 B
  __shared__ int s_src[64], s_dst[64];

  const int tid = threadIdx.x;
  const size_t e0 = (size_t)blockIdx.x * 64;

  if (tid < 64) {
    s_src[tid] = src[e0 + tid];
    s_dst[tid] = dst[e0 + tid];
  }
  // ---- stage WkT (bf16, padded rows) ----
  #pragma unroll
  for (int p = 0; p < 4; ++p) {
    int f = p * 512 + tid;              // 2048 chunks of 8 bf16
    int j = f >> 4, c8 = f & 15;
    *(ushort8v*)&wk_l[j * 136 + c8 * 8] = *(const ushort8v*)&WkT[f * 8];
  }
  __syncthreads();

  // ---- stage kke[i][c] = bf16(k[src_i][c] + e[edge][c]), padded 136 ----
  #pragma unroll
  for (int p = 0; p < 4; ++p) {
    int f = p * 512 + tid;              // 2048 chunks of 4 floats
    int i = f >> 5, c4 = f & 31;
    float4 kv = *(const float4*)&k[(size_t)s_src[i] * DD + c4 * 4];
    float4 ev = *(const float4*)&e[(e0 + i) * DD + c4 * 4];
    ushort4v o = { f2bf(kv.x + ev.x), f2bf(kv.y + ev.y),
                   f2bf(kv.z + ev.z), f2bf(kv.w + ev.w) };
    *(ushort4v*)&kke_l[i * 136 + c4 * 4] = o;
  }
  __syncthreads();

  // ---- phase 1: Ke = kke @ Wk via MFMA. 8 waves: 4 row-groups x 2 col-groups.
  {
    const int lane = tid & 63, wid = tid >> 6;
    const int rg = wid & 3, cg = wid >> 2;
    const int lr = lane & 15, lg = lane >> 4;

    f32x4 acc0 = {0.f,0.f,0.f,0.f}, acc1 = {0.f,0.f,0.f,0.f};
    f32x4 acc2 = {0.f,0.f,0.f,0.f}, acc3 = {0.f,0.f,0.f,0.f};

    const unsigned short* Ab = &kke_l[(rg * 16 + lr) * 136];
    const unsigned short* B0 = &wk_l[(cg * 64 +  0 + lr) * 136];
    const unsigned short* B1 = &wk_l[(cg * 64 + 16 + lr) * 136];
    const unsigned short* B2 = &wk_l[(cg * 64 + 32 + lr) * 136];
    const unsigned short* B3 = &wk_l[(cg * 64 + 48 + lr) * 136];

    #pragma unroll
    for (int kk = 0; kk < 4; ++kk) {
      const int kof = kk * 32 + lg * 8;
      short8 a  = *(const short8*)(Ab + kof);
      acc0 = __builtin_amdgcn_mfma_f32_16x16x32_bf16(a, *(const short8*)(B0 + kof), acc0, 0, 0, 0);
      acc1 = __builtin_amdgcn_mfma_f32_16x16x32_bf16(a, *(const short8*)(B1 + kof), acc1, 0, 0, 0);
      acc2 = __builtin_amdgcn_mfma_f32_16x16x32_bf16(a, *(const short8*)(B2 + kof), acc2, 0, 0, 0);
      acc3 = __builtin_amdgcn_mfma_f32_16x16x32_bf16(a, *(const short8*)(B3 + kof), acc3, 0, 0, 0);
    }

    // D layout: col = lane&15, row = (lane>>4)*4 + r  (m89-verified)
    const int r0 = rg * 16 + lg * 4;
    const int cb = cg * 64 + lr;
    #pragma unroll
    for (int r = 0; r < 4; ++r) {
      ke_l[(r0 + r) * 136 + cb +  0] = f2bf(acc0[r]);
      ke_l[(r0 + r) * 136 + cb + 16] = f2bf(acc1[r]);
      ke_l[(r0 + r) * 136 + cb + 32] = f2bf(acc2[r]);
      ke_l[(r0 + r) * 136 + cb + 48] = f2bf(acc3[r]);
    }
  }
  __syncthreads();   // Ke ready; WkT no longer needed -> wk_l becomes He

  float* He = (float*)wk_l;             // [64][132] f32 (33792 B <= 34816)

  // ---- phase 2: per (edge i, head h) lane ----
  {
    const int i = tid >> 3, h = tid & 7;
    const int sn = s_src[i], dn = s_dst[i];

    float Qr[16];
    #pragma unroll
    for (int d0 = 0; d0 < 4; ++d0) {
      float4 t = *(const float4*)&Qn[(size_t)dn * DD + h * DKK + d0 * 4];
      Qr[d0 * 4] = t.x; Qr[d0 * 4 + 1] = t.y; Qr[d0 * 4 + 2] = t.z; Qr[d0 * 4 + 3] = t.w;
    }

    float sc[8];
    #pragma unroll
    for (int g = 0; g < 8; ++g) {
      const ushort8v* kp = (const ushort8v*)&ke_l[i * 136 + g * DKK];
      ushort8v k0 = kp[0], k1 = kp[1];
      float a = 0.0f;
      #pragma unroll
      for (int t = 0; t < 8; ++t) a = fmaf(Qr[t], bf2f(k0[t]), a);
      #pragma unroll
      for (int t = 0; t < 8; ++t) a = fmaf(Qr[8 + t], bf2f(k1[t]), a);
      a *= 0.25f;
      sc[g] = (a >= 0.0f) ? a : 0.01f * a;
    }

    float mx = sc[0];
    #pragma unroll
    for (int g = 1; g < 8; ++g) mx = fmaxf(mx, sc[g]);
    float sum = 0.0f;
    #pragma unroll
    for (int g = 0; g < 8; ++g) { sc[g] = __expf(sc[g] - mx); sum += sc[g]; }
    float rs = 1.0f / sum;

    float he[16];
    #pragma unroll
    for (int d = 0; d < 16; ++d) he[d] = 0.0f;
    #pragma unroll
    for (int g = 0; g < 8; ++g) {
      float a = sc[g] * rs;
      #pragma unroll
      for (int d0 = 0; d0 < 4; ++d0) {
        float4 vv = *(const float4*)&Vn[(size_t)sn * DD + g * DKK + d0 * 4];
        he[d0 * 4]     = fmaf(a, vv.x, he[d0 * 4]);
        he[d0 * 4 + 1] = fmaf(a, vv.y, he[d0 * 4 + 1]);
        he[d0 * 4 + 2] = fmaf(a, vv.z, he[d0 * 4 + 2]);
        he[d0 * 4 + 3] = fmaf(a, vv.w, he[d0 * 4 + 3]);
      }
    }

    // He writes target wk_l; all wk_l reads finished before the last sync.
    #pragma unroll
    for (int d0 = 0; d0 < 4; ++d0) {
      float4 t = { he[d0 * 4], he[d0 * 4 + 1], he[d0 * 4 + 2], he[d0 * 4 + 3] };
      *(float4*)&He[i * 132 + h * DKK + d0 * 4] = t;
    }
  }
  __syncthreads();

  // ---- coalesced atomic scatter: out[dst_i] += He[i] ----
  #pragma unroll 4
  for (int p = 0; p < 16; ++p) {
    int flat = p * 512 + tid;
    int i2 = flat >> 7, d = flat & 127;
    atomicAdd(&out[(size_t)s_dst[i2] * DD + d], He[i2 * 132 + d]);
  }
}

// ---------------------------------------------------------------------------
extern "C" void kernel_launch(void* const* d_in, const int* in_sizes, int n_in,
                              void* d_out, int out_size, void* d_ws, size_t ws_size,
                              hipStream_t stream) {
  const float* q  = (const float*)d_in[0];
  const float* k  = (const float*)d_in[1];
  const float* v  = (const float*)d_in[2];
  const float* e  = (const float*)d_in[3];
  const int*   src = (const int*)d_in[4];
  const int*   dst = (const int*)d_in[5];
  const float* Wq = (const float*)d_in[6];
  const float* Wk = (const float*)d_in[7];
  const float* Wv = (const float*)d_in[8];

  float* out = (float*)d_out;
  float* ws  = (float*)d_ws;
  float* Qn = ws;                                   // [N,128] f32
  float* Vn = ws + (size_t)NN * DD;                 // [N,128] f32
  unsigned short* WkT = (unsigned short*)(ws + 2 * (size_t)NN * DD);  // [128][128] bf16

  hipMemsetAsync(d_out, 0, (size_t)NN * DD * sizeof(float), stream);
  prep_wkt_kernel<<<DD, DD, 0, stream>>>(Wk, WkT);
  node_proj_kernel<<<(NN + 63) / 64, 256, 0, stream>>>(q, v, Wq, Wv, Qn, Vn);
  edge_attn_kernel<<<EE / 64, 512, 0, stream>>>(k, e, src, dst, WkT, Qn, Vn, out);
}